// Round 11
// baseline (139.783 us; speedup 1.0000x reference)
//
#include <hip/hip_runtime.h>

#define T_TEST 8192
#define BB 8
#define FF 100
#define HH 512

typedef __bf16 bf16x8 __attribute__((ext_vector_type(8)));
typedef __bf16 bf16x2 __attribute__((ext_vector_type(2)));
typedef float f32x16 __attribute__((ext_vector_type(16)));
typedef unsigned short u16;
typedef unsigned int u32;

// HW bf16 convert pair -> packed u32 (compiler emits v_cvt_pk_bf16_f32, RNE)
__device__ __forceinline__ u32 pk2bf(float lo, float hi) {
    bf16x2 t;
    t.x = (__bf16)lo;
    t.y = (__bf16)hi;
    return __builtin_bit_cast(u32, t);
}

__device__ __forceinline__ float nan2num(float v) {
    u32 u = __float_as_uint(v);
    if ((u & 0x7f800000u) == 0x7f800000u) {
        v = (u & 0x007fffffu) ? 0.f : ((u >> 31) ? -3.3895314e38f : 3.3895314e38f);
    }
    return v;
}

// ---- combined weight prep: 32x32x16 fragment-major layouts (UNCHANGED) --
// A-frag (w): h = lane&31, k = (lane>>5)*8 + j, 8 bf16/lane.
// w1f frag idx: ((b*8  + ks)*16 + n32)*64 + lane   (ks 0..7; kernel uses 0..6)
//   BIAS TRICK: row k=FF(=100) of w1f carries b1 (fused stages x[*][100]=1.0,
//   so the layer-1 MFMA adds b1 for free -- zero regs/instructions in fused).
// w2f frag idx: ((b*32 + ks)*16 + n32)*64 + lane   (ks 0..31)
__global__ void prep_w(const float* __restrict__ w1, const float* __restrict__ b1,
                       const float* __restrict__ w2,
                       u16* __restrict__ w1f, u16* __restrict__ w2f) {
    int bid = blockIdx.x;
    if (bid < 256) {                      // w1f
        int t = bid * 256 + threadIdx.x;
        int lane = t & 63;
        int n32 = (t >> 6) & 15;
        int b = t >> 13;
        int n = n32 * 32 + (lane & 31);
        int kb = ((t >> 10) & 7) * 16 + (lane >> 5) * 8;
        u32 p[4];
#pragma unroll
        for (int jp = 0; jp < 4; ++jp) {
            int k0 = kb + jp * 2;
            float v0 = (k0 < FF)     ? w1[(b * FF + k0) * HH + n]
                     : ((k0 == FF)     ? b1[b * HH + n] : 0.f);
            float v1 = (k0 + 1 < FF) ? w1[(b * FF + k0 + 1) * HH + n]
                     : ((k0 + 1 == FF) ? b1[b * HH + n] : 0.f);
            p[jp] = pk2bf(v0, v1);
        }
        uint4 o = {p[0], p[1], p[2], p[3]};
        *(uint4*)(w1f + (size_t)t * 8) = o;
    } else {                              // w2f
        int t = (bid - 256) * 256 + threadIdx.x;
        int lane = t & 63;
        int n32 = (t >> 6) & 15;
        int b = t >> 15;
        int n = n32 * 32 + (lane & 31);
        int kb = ((t >> 10) & 31) * 16 + (lane >> 5) * 8;
        u32 p[4];
#pragma unroll
        for (int jp = 0; jp < 4; ++jp) {
            int k0 = kb + jp * 2;
            float v0 = w2[(b * HH + k0) * HH + n];
            float v1 = w2[(b * HH + k0 + 1) * HH + n];
            p[jp] = pk2bf(v0, v1);
        }
        uint4 o = {p[0], p[1], p[2], p[3]};
        *(uint4*)(w2f + (size_t)t * 8) = o;
    }
}

// ---- fused 3-layer MLP, OPERAND-SWAPPED, M=32 OCCUPANCY REDESIGN -------
// R10 was latency-bound with occupancy double-capped (LDS 80K -> 2 blocks;
// VGPR 128 -> 16 waves). M=32: LDS 40K + ~70-80 VGPR -> 24 waves/CU.
//   * acc [2] (32 regs), pa ring-2 x1 (8), pb ring-2 (16)
//   * __launch_bounds__(512, 6): 3 blocks x 8 waves = 6 waves/SIMD, cap ~85
//   * staging split across lh halves (one uint4 store/lane)
// C layout (swapped mfma): col(=lane&31) = ROW m, regs = h.
// Proven spill triggers kept out: s_setprio, pointer-XOR swizzles, bias
// transients near acc windows. Tripwire: WRITE_SIZE >10MB => cap exceeded.
__global__ __launch_bounds__(512, 6) void fused_mlp(
    const float* __restrict__ x, const u16* __restrict__ w1f,
    const u16* __restrict__ w2f, const float* __restrict__ b2,
    const float* __restrict__ w3, const float* __restrict__ b3,
    float* __restrict__ out) {
    __shared__ __align__(16) char lds[40960];
    u16* xf  = (u16*)lds;                  // x frags, 7 KB used (fi = ks1), 8 KB resv
    u16* h1f = (u16*)(lds + 8192);         // h1 frags, 32 KB (fi = ks)

    const int tid = threadIdx.x;
    const int b = blockIdx.x;              // batch -> XCD affinity
    const int m0 = blockIdx.y * 32;
    const int lane = tid & 63;
    const int ws = __builtin_amdgcn_readfirstlane(tid >> 6);
    const int l31 = lane & 31, lh = lane >> 5;
    const int n32b = ws * 2;               // wave's 2 h-blocks (M-side)
    const int r2 = ws * 4;                 // layer-2 K-phase (max 28)

    const bf16x8* W1 = (const bf16x8*)w1f + (size_t)b * 8192;
    const bf16x8* W2 = (const bf16x8*)w2f + (size_t)b * 32768;

    bf16x8 pa[2], pb[2][2];                // pa = x/h1 frag ring-2; pb = w ring-2

    // layer-1 W prologue: stages 0..1 in flight across x staging
#pragma unroll
    for (int s = 0; s < 2; ++s)
#pragma unroll
        for (int hi = 0; hi < 2; ++hi)
            pb[s][hi] = W1[(s * 16 + n32b + hi) * 64 + lane];

    // ---- stage x: thread (row=l31, ks1=ws, khalf=lh); K1=112, k100 = 1.0 ----
    if (ws < 7) {
        const float* xr = x + ((size_t)(m0 + l31) * BB + b) * FF + ws * 16 + lh * 8;
        u32 p[4] = {0u, 0u, 0u, 0u};
        if (ws < 6) {                      // k = ws*16 + lh*8 + 0..7, all real
            float4 v0 = *(const float4*)(xr);
            float4 v1 = *(const float4*)(xr + 4);
            p[0] = pk2bf(nan2num(v0.x), nan2num(v0.y));
            p[1] = pk2bf(nan2num(v0.z), nan2num(v0.w));
            p[2] = pk2bf(nan2num(v1.x), nan2num(v1.y));
            p[3] = pk2bf(nan2num(v1.z), nan2num(v1.w));
        } else if (lh == 0) {              // k 96..99 real, k100 = 1.0 (b1 slot)
            float4 v0 = *(const float4*)(xr);
            p[0] = pk2bf(nan2num(v0.x), nan2num(v0.y));
            p[1] = pk2bf(nan2num(v0.z), nan2num(v0.w));
            p[2] = 0x3F80u;                // bf16(1.0) @k100, 0 @k101
        }                                  // s==6,lh==1: k104..111 zeros
        uint4 g = {p[0], p[1], p[2], p[3]};
        *(uint4*)((char*)xf + ws * 1024 + lh * 512 + l31 * 16) = g;
    }
    __syncthreads();

    // ---- layer 1: 7 k-steps (K=112), pb ring-2, pa ring-2, SWAPPED mfma ----
    f32x16 acc1[2] = {};                   // bias via k=100 slot
#pragma unroll
    for (int s = 0; s < 2; ++s)
        pa[s] = *(const bf16x8*)((char*)xf + s * 1024 + lane * 16);
#pragma unroll
    for (int ks = 0; ks < 7; ++ks) {
        const int pA = ks & 1, pB = ks & 1;
        bf16x8 a0 = pa[pA];                // x frag (rows)
        bf16x8 b0 = pb[pB][0], b1r = pb[pB][1];  // w frags (h)
        if (ks < 5) {
            pa[pA] = *(const bf16x8*)((char*)xf + (ks + 2) * 1024 + lane * 16);
#pragma unroll
            for (int hi = 0; hi < 2; ++hi)
                pb[pB][hi] = W1[((ks + 2) * 16 + n32b + hi) * 64 + lane];
        }
        acc1[0] = __builtin_amdgcn_mfma_f32_32x32x16_bf16(b0,  a0, acc1[0], 0, 0, 0);
        acc1[1] = __builtin_amdgcn_mfma_f32_32x32x16_bf16(b1r, a0, acc1[1], 0, 0, 0);
    }

    // layer-2 W prologue: stages r2, r2+1 (r2+1 <= 29, no wrap)
#pragma unroll
    for (int s = 0; s < 2; ++s)
#pragma unroll
        for (int hi = 0; hi < 2; ++hi)
            pb[s][hi] = W2[((r2 + s) * 16 + n32b + hi) * 64 + lane];

    // ---- epilogue 1: relu(acc1) -> h1f, NO cross-lane (bias already in) ----
    // lane (l31,lh): h1[h=ws*64+hi*32+q*8+4lh+i][m=l31] -> frag ks2=ws*4+hi*2+(q>>1),
    // khalf=q&1, j=4lh+i; one b64 per (hi,q).
    {
        char* hwB = (char*)h1f + ws * 4096 + l31 * 16 + lh * 8;
#pragma unroll
        for (int hi = 0; hi < 2; ++hi)
#pragma unroll
            for (int q = 0; q < 4; ++q) {
                uint2 o;
                o.x = pk2bf(fmaxf(acc1[hi][q * 4 + 0], 0.f),
                            fmaxf(acc1[hi][q * 4 + 1], 0.f));
                o.y = pk2bf(fmaxf(acc1[hi][q * 4 + 2], 0.f),
                            fmaxf(acc1[hi][q * 4 + 3], 0.f));
                *(uint2*)(hwB + hi * 2048 + (q >> 1) * 1024 + (q & 1) * 512) = o;
            }
    }
    __syncthreads();

    // ---- layer 2: 32 k-steps, K-phase r2, pb ring-2, pa ring-2, SWAPPED ----
    f32x16 acc2[2] = {};                   // b2 folded into layer-3 reduction
    const char* hv  = (const char*)h1f + r2 * 1024 + (size_t)lane * 16;
    const char* hvB = hv - 32768;
#pragma unroll
    for (int s = 0; s < 2; ++s)
        pa[s] = *(const bf16x8*)(hv + s * 1024);   // r2+1 <= 29 < 32, no wrap
#pragma unroll
    for (int ks = 0; ks < 32; ++ks) {
        const int pA = ks & 1, pB = ks & 1;
        bf16x8 a0 = pa[pA];
        bf16x8 b0 = pb[pB][0], b1r = pb[pB][1];
        if (ks < 30) {
            const int k2 = ks + 2;
            const char* hp = (k2 + r2 < 32) ? hv : hvB;
            pa[pA] = *(const bf16x8*)(hp + k2 * 1024);
            int kspf = k2 + r2;
            kspf -= (kspf >= 32) ? 32 : 0;
#pragma unroll
            for (int hi = 0; hi < 2; ++hi)
                pb[pB][hi] = W2[(kspf * 16 + n32b + hi) * 64 + lane];
        }
        acc2[0] = __builtin_amdgcn_mfma_f32_32x32x16_bf16(b0,  a0, acc2[0], 0, 0, 0);
        acc2[1] = __builtin_amdgcn_mfma_f32_32x32x16_bf16(b1r, a0, acc2[1], 0, 0, 0);
    }

    // ---- layer 3: in-register fold with b2+w3 (pa/pb dead -> headroom) ----
    // lane (l31,lh): partial for row l31 over its 32 h2 values; 16 partials/row.
    float* part = (float*)xf;              // xf dead after L1 (all waves past barrier)
    {
        float v = 0.f;
#pragma unroll
        for (int hi = 0; hi < 2; ++hi)
#pragma unroll
            for (int q = 0; q < 4; ++q) {
                const float4 bq = *(const float4*)(b2 + b * HH + ws * 64 + hi * 32 + q * 8 + lh * 4);
                const float4 wq = *(const float4*)(w3 + b * HH + ws * 64 + hi * 32 + q * 8 + lh * 4);
                float bl[4] = {bq.x, bq.y, bq.z, bq.w};
                float wl[4] = {wq.x, wq.y, wq.z, wq.w};
#pragma unroll
                for (int i = 0; i < 4; ++i)
                    v = fmaf(fmaxf(acc2[hi][q * 4 + i] + bl[i], 0.f), wl[i], v);
            }
        part[(ws * 2 + lh) * 32 + l31] = v;
    }
    __syncthreads();
    if (tid < 32) {
        float s = b3[b];
#pragma unroll
        for (int p = 0; p < 16; ++p) s += part[p * 32 + tid];
        out[(size_t)(m0 + tid) * BB + b] = s;
    }
}

extern "C" void kernel_launch(void* const* d_in, const int* in_sizes, int n_in,
                              void* d_out, int out_size, void* d_ws, size_t ws_size,
                              hipStream_t stream) {
    const float* x  = (const float*)d_in[0];
    const float* w1 = (const float*)d_in[1];
    const float* b1 = (const float*)d_in[2];
    const float* w2 = (const float*)d_in[3];
    const float* b2 = (const float*)d_in[4];
    const float* w3 = (const float*)d_in[5];
    const float* b3 = (const float*)d_in[6];
    float* out = (float*)d_out;

    u16* w1f = (u16*)d_ws;                              // 1 MB
    u16* w2f = w1f + (size_t)BB * 8192 * 8;             // 4 MB

    prep_w<<<1280, 256, 0, stream>>>(w1, b1, w2, w1f, w2f);

    // grid.x = batch (XCD affinity), grid.y = 32-row tile
    fused_mlp<<<dim3(BB, T_TEST / 32), 512, 0, stream>>>(
        x, w1f, w2f, b2, w3, b3, out);
}

// Round 12
// 126.176 us; speedup vs baseline: 1.1078x; 1.1078x over previous
//
#include <hip/hip_runtime.h>

#define T_TEST 8192
#define BB 8
#define FF 100
#define HH 512

typedef __bf16 bf16x8 __attribute__((ext_vector_type(8)));
typedef __bf16 bf16x2 __attribute__((ext_vector_type(2)));
typedef float f32x16 __attribute__((ext_vector_type(16)));
typedef unsigned short u16;
typedef unsigned int u32;

// HW bf16 convert pair -> packed u32 (compiler emits v_cvt_pk_bf16_f32, RNE)
__device__ __forceinline__ u32 pk2bf(float lo, float hi) {
    bf16x2 t;
    t.x = (__bf16)lo;
    t.y = (__bf16)hi;
    return __builtin_bit_cast(u32, t);
}

__device__ __forceinline__ float nan2num(float v) {
    u32 u = __float_as_uint(v);
    if ((u & 0x7f800000u) == 0x7f800000u) {
        v = (u & 0x007fffffu) ? 0.f : ((u >> 31) ? -3.3895314e38f : 3.3895314e38f);
    }
    return v;
}

// ---- combined weight prep: 32x32x16 fragment-major layouts -------------
// A-frag (w): h = lane&31, k = (lane>>5)*8 + j, 8 bf16/lane.
// w1f frag idx: ((b*8  + ks)*16 + n32)*64 + lane   (ks 0..7; kernel uses 0..6)
//   BIAS TRICK: row k=FF(=100) of w1f carries b1 (fused stages x[*][100]=1.0,
//   so the layer-1 MFMA adds b1 for free -- zero regs/instructions in fused).
// w2f frag idx: ((b*32 + ks)*16 + n32)*64 + lane   (ks 0..31)
__global__ void prep_w(const float* __restrict__ w1, const float* __restrict__ b1,
                       const float* __restrict__ w2,
                       u16* __restrict__ w1f, u16* __restrict__ w2f) {
    int bid = blockIdx.x;
    if (bid < 256) {                      // w1f
        int t = bid * 256 + threadIdx.x;
        int lane = t & 63;
        int n32 = (t >> 6) & 15;
        int b = t >> 13;
        int n = n32 * 32 + (lane & 31);
        int kb = ((t >> 10) & 7) * 16 + (lane >> 5) * 8;
        u32 p[4];
#pragma unroll
        for (int jp = 0; jp < 4; ++jp) {
            int k0 = kb + jp * 2;
            float v0 = (k0 < FF)     ? w1[(b * FF + k0) * HH + n]
                     : ((k0 == FF)     ? b1[b * HH + n] : 0.f);
            float v1 = (k0 + 1 < FF) ? w1[(b * FF + k0 + 1) * HH + n]
                     : ((k0 + 1 == FF) ? b1[b * HH + n] : 0.f);
            p[jp] = pk2bf(v0, v1);
        }
        uint4 o = {p[0], p[1], p[2], p[3]};
        *(uint4*)(w1f + (size_t)t * 8) = o;
    } else {                              // w2f
        int t = (bid - 256) * 256 + threadIdx.x;
        int lane = t & 63;
        int n32 = (t >> 6) & 15;
        int b = t >> 15;
        int n = n32 * 32 + (lane & 31);
        int kb = ((t >> 10) & 31) * 16 + (lane >> 5) * 8;
        u32 p[4];
#pragma unroll
        for (int jp = 0; jp < 4; ++jp) {
            int k0 = kb + jp * 2;
            float v0 = w2[(b * HH + k0) * HH + n];
            float v1 = w2[(b * HH + k0 + 1) * HH + n];
            p[jp] = pk2bf(v0, v1);
        }
        uint4 o = {p[0], p[1], p[2], p[3]};
        *(uint4*)(w2f + (size_t)t * 8) = o;
    }
}

// ---- fused 3-layer MLP, OPERAND-SWAPPED: mfma(w_frag, x_frag) ----------
// [R10 restoration -- best verified: 51.6-52.7 us fused / 126.8 us total]
// C layout: col(=lane&31) = ROW m, regs = h (crow(r,lh) = (r&3)+8*(r>>2)+4*lh).
// => epilogue-1: pk2bf on adjacent regs + 16x ds_write_b64, NO cross-lane.
// => layer-3: h-reduction IN-REGISTER (fmax+fma), NO dpp/shfl chains.
// BIAS: b1 rides the k=100 MFMA slot (see prep_w); b2 folded into layer-3
// where pa/pb are dead. acc1/acc2 = {}.
// REGISTER BUDGET: hard cap 128/wave at (512,4). Proven spill triggers kept
// out: s_setprio (R3/R4/R6), pointer-XOR swizzles (R4), rings >4 (R3),
// bias transients near acc windows (R9).
// Structure verdicts from this session: M=32 occupancy redesign REGRESSED
// (R11: per-block overhead 2x + ring cover halved); LDS swizzle ~1 us max
// and risky (R5); bottleneck = MFMA(17us) + per-CU L2 W2-stream (~15us) +
// LDS pipe (~10us) with imperfect overlap at the 128-reg cap.
__global__ __launch_bounds__(512, 4) void fused_mlp(
    const float* __restrict__ x, const u16* __restrict__ w1f,
    const u16* __restrict__ w2f, const float* __restrict__ b2,
    const float* __restrict__ w3, const float* __restrict__ b3,
    float* __restrict__ out) {
    __shared__ __align__(16) char lds[81920];
    u16* xf  = (u16*)lds;                  // x frags, 16 KB (fi = ks1*2+rb)
    u16* h1f = (u16*)(lds + 16384);        // h1 frags, 64 KB (fi = ks*2+rb)

    const int tid = threadIdx.x;
    const int b = blockIdx.x;              // batch -> XCD affinity (x + 8y % 8 = b)
    const int m0 = blockIdx.y * 64;
    const int lane = tid & 63;
    const int ws = __builtin_amdgcn_readfirstlane(tid >> 6);
    const int l31 = lane & 31, lh = lane >> 5;
    const int n32b = ws * 2;               // wave's 2 h-blocks (M-side)
    const int r2 = ws * 4;                 // layer-2 K-phase (own slices first)

    const bf16x8* W1 = (const bf16x8*)w1f + (size_t)b * 8192;
    const bf16x8* W2 = (const bf16x8*)w2f + (size_t)b * 32768;

    bf16x8 pa[2][2], pb[4][2];             // pa = x/h1 frags (LDS), pb = w frags

    // layer-1 W prologue: stages 0..3 in flight across x staging
#pragma unroll
    for (int s = 0; s < 4; ++s)
#pragma unroll
        for (int hi = 0; hi < 2; ++hi)
            pb[s][hi] = W1[(s * 16 + n32b + hi) * 64 + lane];

    // ---- stage x in frag order (B/N-side operand): thread = (row=lane, ks1=ws)
    // K1=112; k=100 carries the constant 1.0 for the b1 MFMA bias trick.
    if (ws < 7) {
        int row = lane, s = ws;
        int rb = row >> 5, m = row & 31;
        const float* xr = x + ((size_t)(m0 + row) * BB + b) * FF + s * 16;
        u32 p[8];
#pragma unroll
        for (int i = 0; i < 8; ++i) p[i] = 0;
        if (s <= 5) {
#pragma unroll
            for (int j = 0; j < 4; ++j) {
                float4 v = *(const float4*)(xr + j * 4);
                p[j * 2 + 0] = pk2bf(nan2num(v.x), nan2num(v.y));
                p[j * 2 + 1] = pk2bf(nan2num(v.z), nan2num(v.w));
            }
        } else {                           // s == 6: k 96..99 real, k100 = 1.0
            float4 v = *(const float4*)(xr);
            p[0] = pk2bf(nan2num(v.x), nan2num(v.y));
            p[1] = pk2bf(nan2num(v.z), nan2num(v.w));
            p[2] = 0x3F80u;                // bf16(1.0) in k=100, k=101 = 0
        }
        int fi1 = s * 2 + rb;
        uint4 g0 = {p[0], p[1], p[2], p[3]};
        uint4 g1 = {p[4], p[5], p[6], p[7]};
        *(uint4*)(xf + (fi1 * 64 + m) * 8)      = g0;   // khalf 0
        *(uint4*)(xf + (fi1 * 64 + 32 + m) * 8) = g1;   // khalf 1
    }
    __syncthreads();

    // ---- layer 1: 7 k-steps (K=112), pb ring-4, pa ring-2, SWAPPED mfma ----
    f32x16 acc1[2][2] = {};                // bias via k=100 slot
#pragma unroll
    for (int s = 0; s < 2; ++s)
#pragma unroll
        for (int rb = 0; rb < 2; ++rb)
            pa[s][rb] = *(const bf16x8*)(xf + ((s * 2 + rb) * 64 + lane) * 8);
#pragma unroll
    for (int ks = 0; ks < 7; ++ks) {
        const int pA = ks & 1, pB = ks & 3;
        bf16x8 a0 = pa[pA][0], a1 = pa[pA][1];       // x frags (rows)
        bf16x8 b0 = pb[pB][0], b1r = pb[pB][1];      // w frags (h)
        if (ks < 5) {
#pragma unroll
            for (int rb = 0; rb < 2; ++rb)
                pa[pA][rb] = *(const bf16x8*)(xf + (((ks + 2) * 2 + rb) * 64 + lane) * 8);
        }
        if (ks < 3) {
#pragma unroll
            for (int hi = 0; hi < 2; ++hi)
                pb[pB][hi] = W1[((ks + 4) * 16 + n32b + hi) * 64 + lane];
        }
        acc1[0][0] = __builtin_amdgcn_mfma_f32_32x32x16_bf16(b0,  a0, acc1[0][0], 0, 0, 0);
        acc1[0][1] = __builtin_amdgcn_mfma_f32_32x32x16_bf16(b0,  a1, acc1[0][1], 0, 0, 0);
        acc1[1][0] = __builtin_amdgcn_mfma_f32_32x32x16_bf16(b1r, a0, acc1[1][0], 0, 0, 0);
        acc1[1][1] = __builtin_amdgcn_mfma_f32_32x32x16_bf16(b1r, a1, acc1[1][1], 0, 0, 0);
    }

    // layer-2 W prologue: stages r2..r2+3 (in flight across epilogue + barrier)
#pragma unroll
    for (int s = 0; s < 4; ++s) {
        int k = (r2 + s) & 31;
#pragma unroll
        for (int hi = 0; hi < 2; ++hi)
            pb[s][hi] = W2[(k * 16 + n32b + hi) * 64 + lane];
    }

    // ---- epilogue 1: relu(acc1) -> h1f, NO cross-lane (bias already in) ----
    // lane (l31,lh) holds h1[h=ws*64+hi*32+crow(r,lh)][m=l31(+32rb)].
    // quad q -> frag ks2 = 4ws+2hi+(q>>1), khalf2 = q&1; one b64/quad.
    {
        char* hwB = (char*)h1f + ws * 8192 + l31 * 16 + lh * 8;
#pragma unroll
        for (int hi = 0; hi < 2; ++hi)
#pragma unroll
            for (int rb = 0; rb < 2; ++rb)
#pragma unroll
                for (int q = 0; q < 4; ++q) {
                    uint2 o;
                    o.x = pk2bf(fmaxf(acc1[hi][rb][q * 4 + 0], 0.f),
                                fmaxf(acc1[hi][rb][q * 4 + 1], 0.f));
                    o.y = pk2bf(fmaxf(acc1[hi][rb][q * 4 + 2], 0.f),
                                fmaxf(acc1[hi][rb][q * 4 + 3], 0.f));
                    *(uint2*)(hwB + hi * 4096 + rb * 1024 +
                              (q >> 1) * 2048 + (q & 1) * 512) = o;
                }
    }
    __syncthreads();

    // ---- layer 2: 32 k-steps, K-phase r2, pb ring-4, pa ring-2, SWAPPED ----
    f32x16 acc2[2][2] = {};                // b2 folded into layer-3 reduction
    const char* hv  = (const char*)h1f + r2 * 2048 + (size_t)lane * 16;
    const char* hvB = hv - 65536;
#pragma unroll
    for (int s = 0; s < 2; ++s) {
        const char* hp = (s + r2 < 32) ? hv : hvB;
#pragma unroll
        for (int rb = 0; rb < 2; ++rb)
            pa[s][rb] = *(const bf16x8*)(hp + s * 2048 + rb * 1024);
    }
#pragma unroll
    for (int ks = 0; ks < 32; ++ks) {
        const int pA = ks & 1, pB = ks & 3;
        bf16x8 a0 = pa[pA][0], a1 = pa[pA][1];
        bf16x8 b0 = pb[pB][0], b1r = pb[pB][1];
        if (ks < 30) {
            const char* hp = (ks + 2 + r2 < 32) ? hv : hvB;
#pragma unroll
            for (int rb = 0; rb < 2; ++rb)
                pa[pA][rb] = *(const bf16x8*)(hp + (ks + 2) * 2048 + rb * 1024);
        }
        if (ks < 28) {
            int kspf = ks + 4 + r2;
            kspf -= (kspf >= 32) ? 32 : 0;
#pragma unroll
            for (int hi = 0; hi < 2; ++hi)
                pb[pB][hi] = W2[(kspf * 16 + n32b + hi) * 64 + lane];
        }
        acc2[0][0] = __builtin_amdgcn_mfma_f32_32x32x16_bf16(b0,  a0, acc2[0][0], 0, 0, 0);
        acc2[0][1] = __builtin_amdgcn_mfma_f32_32x32x16_bf16(b0,  a1, acc2[0][1], 0, 0, 0);
        acc2[1][0] = __builtin_amdgcn_mfma_f32_32x32x16_bf16(b1r, a0, acc2[1][0], 0, 0, 0);
        acc2[1][1] = __builtin_amdgcn_mfma_f32_32x32x16_bf16(b1r, a1, acc2[1][1], 0, 0, 0);
    }

    // ---- layer 3: in-register fold with b2+w3 (pa/pb dead -> reg headroom);
    // hi-outer so acc2[0] dies before hi=1's loads. Peak live ~100 regs.
    float* part = (float*)xf;
    {
        float v0 = 0.f, v1 = 0.f;
#pragma unroll
        for (int hi = 0; hi < 2; ++hi) {
#pragma unroll
            for (int q = 0; q < 4; ++q) {
                const float4 bq = *(const float4*)(b2 + b * HH + ws * 64 + hi * 32 + q * 8 + lh * 4);
                const float4 wq = *(const float4*)(w3 + b * HH + ws * 64 + hi * 32 + q * 8 + lh * 4);
                float bl[4] = {bq.x, bq.y, bq.z, bq.w};
                float wl[4] = {wq.x, wq.y, wq.z, wq.w};
#pragma unroll
                for (int i = 0; i < 4; ++i) {
                    v0 = fmaf(fmaxf(acc2[hi][0][q * 4 + i] + bl[i], 0.f), wl[i], v0);
                    v1 = fmaf(fmaxf(acc2[hi][1][q * 4 + i] + bl[i], 0.f), wl[i], v1);
                }
            }
        }
        part[(ws * 2 + lh) * 64 + l31] = v0;
        part[(ws * 2 + lh) * 64 + 32 + l31] = v1;
    }
    __syncthreads();
    if (tid < 64) {
        float s = b3[b];
#pragma unroll
        for (int ww = 0; ww < 16; ++ww) s += part[ww * 64 + tid];
        out[(size_t)(m0 + tid) * BB + b] = s;
    }
}

extern "C" void kernel_launch(void* const* d_in, const int* in_sizes, int n_in,
                              void* d_out, int out_size, void* d_ws, size_t ws_size,
                              hipStream_t stream) {
    const float* x  = (const float*)d_in[0];
    const float* w1 = (const float*)d_in[1];
    const float* b1 = (const float*)d_in[2];
    const float* w2 = (const float*)d_in[3];
    const float* b2 = (const float*)d_in[4];
    const float* w3 = (const float*)d_in[5];
    const float* b3 = (const float*)d_in[6];
    float* out = (float*)d_out;

    u16* w1f = (u16*)d_ws;                              // 1 MB
    u16* w2f = w1f + (size_t)BB * 8192 * 8;             // 4 MB

    prep_w<<<1280, 256, 0, stream>>>(w1, b1, w2, w1f, w2f);

    // grid.x = batch (XCD affinity), grid.y = 64-row tile
    fused_mlp<<<dim3(BB, T_TEST / 64), 512, 0, stream>>>(
        x, w1f, w2f, b2, w3, b3, out);
}